// Round 2
// baseline (911.268 us; speedup 1.0000x reference)
//
#include <hip/hip_runtime.h>
#include <hip/hip_cooperative_groups.h>

namespace cg = cooperative_groups;

#define NIMG 16
#define HH 512
#define WW 512
#define HW (HH * WW)
#define NHW (NIMG * HW)
#define TILE 64
#define TILE_AREA (TILE * TILE)

#define EPSV ((float)(216.0 / 24389.0))
#define KAPV ((float)(24389.0 / 27.0))

// ---------- fast transcendental helpers (unchanged, verified) ----------

__device__ __forceinline__ float pow24(float t) {
    float l   = __builtin_amdgcn_logf(t);
    float r   = __builtin_amdgcn_exp2f(l);
    float dl  = (t - r) * __builtin_amdgcn_rcpf(r) * 1.4426950408889634f;
    float ehi = 2.4f * l;
    float elo = __builtin_fmaf(2.4f, l, -ehi) + 2.4f * dl;
    float p   = __builtin_amdgcn_exp2f(ehi);
    return __builtin_fmaf(p * 0.6931471805599453f, elo, p);
}

__device__ __forceinline__ float cbrt_p(float v) {
    float l  = __builtin_amdgcn_logf(v);
    float t  = __builtin_amdgcn_exp2f(l * (1.0f / 3.0f));
    float t2 = t * t;
    float num = __builtin_fmaf(-t2, t, v);
    return __builtin_fmaf(num, __builtin_amdgcn_rcpf(3.0f * t2), t);
}

__device__ __forceinline__ float srgb2lin_p(float c) {
    float lin = c / 12.92f;
    float t   = (c + 0.055f) / 1.055f;
    return (c <= 0.04045f) ? lin : pow24(t);
}

__device__ __forceinline__ float fwd_p(float v) {
    return (v > EPSV) ? cbrt_p(v) : (KAPV * v + 16.0f) / 116.0f;
}

__device__ __forceinline__ float lin2srgb_f(float c) {
    c = fmaxf(c, 0.0f);
    float lo = c * 12.92f;
    float p  = __builtin_amdgcn_exp2f(__builtin_amdgcn_logf(c) * (float)(1.0 / 2.4));
    float hi = 1.055f * p - 0.055f;
    float r  = (c <= 0.0031308f) ? lo : hi;
    return fminf(fmaxf(r, 0.0f), 1.0f);
}

__device__ __forceinline__ float finv_f(float f) {
    float f3 = f * f * f;
    return (f3 > EPSV) ? f3 : (116.0f * f - 16.0f) * (float)(27.0 / 24389.0);
}

__device__ __forceinline__ void lab2rgb255_f(float L, float a, float b,
                                             float* R, float* G, float* B) {
    float fy = (L + 16.0f) * (float)(1.0 / 116.0);
    float fx = fy + a * (float)(1.0 / 500.0);
    float fz = fy - b * (float)(1.0 / 200.0);
    float X = finv_f(fx) * 0.95047f;
    float Y = finv_f(fy);
    float Z = finv_f(fz) * 1.08883f;
    *R = lin2srgb_f((float)3.2404542 * X + (float)-1.5371385 * Y + (float)-0.4985314 * Z) * 255.0f;
    *G = lin2srgb_f((float)-0.969266 * X + (float)1.8760108  * Y + (float)0.041556   * Z) * 255.0f;
    *B = lin2srgb_f((float)0.0556434 * X + (float)-0.2040259 * Y + (float)1.0572252  * Z) * 255.0f;
}

// agent-scope coherent helpers: cross-XCD-safe regardless of grid.sync fencing
__device__ __forceinline__ void ast_f(float* p, float v) {
    __hip_atomic_store(p, v, __ATOMIC_RELEASE, __HIP_MEMORY_SCOPE_AGENT);
}
__device__ __forceinline__ float ald_f(const float* p) {
    return __hip_atomic_load(p, __ATOMIC_ACQUIRE, __HIP_MEMORY_SCOPE_AGENT);
}
__device__ __forceinline__ void ast_i(int* p, int v) {
    __hip_atomic_store(p, v, __ATOMIC_RELEASE, __HIP_MEMORY_SCOPE_AGENT);
}
__device__ __forceinline__ int ald_i(const int* p) {
    return __hip_atomic_load(p, __ATOMIC_ACQUIRE, __HIP_MEMORY_SCOPE_AGENT);
}

// ================= fused cooperative kernel =================
// One block per 64x64 tile; grid 64x16 = 1024 blocks = 4 blocks/CU.
// ALL cross-block data (tmn/tmx, hist_img, lut_tile) moves via agent-scope
// atomics — plain stores/loads across grid.sync() are not cross-XCD safe
// (per-XCD L2 non-coherence was the round-1 failure).
__global__ __launch_bounds__(256, 4)
void k_fused(const float* __restrict__ x, float* __restrict__ out,
             float* __restrict__ tmn, float* __restrict__ tmx,
             int* __restrict__ hist_img, float* __restrict__ lut_tile) {
    const int n = blockIdx.y, tile = blockIdx.x;
    const int b = (n << 6) + tile;
    const int ty = tile >> 3, tx = tile & 7;
    const int t = threadIdx.x;

    __shared__ int   sh[256];
    __shared__ float smn[4], smx[4];
    __shared__ float sred2[2];
    __shared__ int   wsum[4];
    __shared__ float seq[256];
    __shared__ float slut[9 * 256];

    // persistent per-thread pixel data (16 px/thread)
    float Lr[16], Ar[16], Brr[16];

    const float* img = x + (size_t)n * 3 * HW;

    // ---------------- phase 1: RGB -> Lab, tile min/max ----------------
    float mn = 1e30f, mx = -1e30f;
    #pragma unroll
    for (int it = 0; it < 4; it++) {
        int j = it * 1024 + t * 4;
        int r = j >> 6, c = j & 63;
        int p = (ty * TILE + r) * WW + tx * TILE + c;
        float4 r4 = *(const float4*)(img + p);
        float4 g4 = *(const float4*)(img + HW + p);
        float4 b4 = *(const float4*)(img + 2 * HW + p);
        #pragma unroll
        for (int k = 0; k < 4; k++) {
            float rr = ((const float*)&r4)[k];
            float gg = ((const float*)&g4)[k];
            float bb = ((const float*)&b4)[k];
            float rl = srgb2lin_p(rr), gl = srgb2lin_p(gg), bl = srgb2lin_p(bb);
            float X = ((float)0.4124564 * rl + (float)0.3575761 * gl + (float)0.1804375 * bl) / (float)0.95047;
            float Y = ((float)0.2126729 * rl + (float)0.7151522 * gl + (float)0.072175  * bl);
            float Z = ((float)0.0193339 * rl + (float)0.119192  * gl + (float)0.9503041 * bl) / (float)1.08883;
            float fx = fwd_p(X), fy = fwd_p(Y), fz = fwd_p(Z);
            float L = 116.0f * fy - 16.0f;
            Lr[it * 4 + k]  = L;
            Ar[it * 4 + k]  = 500.0f * (fx - fy);
            Brr[it * 4 + k] = 200.0f * (fy - fz);
            mn = fminf(mn, L);
            mx = fmaxf(mx, L);
        }
    }
    for (int off = 32; off; off >>= 1) {
        mn = fminf(mn, __shfl_down(mn, off, 64));
        mx = fmaxf(mx, __shfl_down(mx, off, 64));
    }
    const int wv = t >> 6, ln = t & 63;
    if (ln == 0) { smn[wv] = mn; smx[wv] = mx; }
    __syncthreads();
    if (t == 0) {
        ast_f(&tmn[b], fminf(fminf(smn[0], smn[1]), fminf(smn[2], smn[3])));
        ast_f(&tmx[b], fmaxf(fmaxf(smx[0], smx[1]), fmaxf(smx[2], smx[3])));
    }
    // zero the per-image hist (workspace is poisoned between runs)
    if (tile == 0) ast_i(&hist_img[(n << 8) + t], 0);
    __threadfence();

    cg::grid_group g = cg::this_grid();
    g.sync();

    // -------- phase 2: image min/max, quantize, hist, CLAHE LUT --------
    if (t < 64) {
        float v = ald_f(&tmn[(n << 6) + t]);
        for (int off = 32; off; off >>= 1) v = fminf(v, __shfl_down(v, off, 64));
        if (t == 0) sred2[0] = v;
    } else if (t < 128) {
        float v = ald_f(&tmx[(n << 6) + (t - 64)]);
        for (int off = 32; off; off >>= 1) v = fmaxf(v, __shfl_down(v, off, 64));
        if (t == 64) sred2[1] = v;
    }
    sh[t] = 0;
    __syncthreads();
    float lmin = sred2[0], lmax = sred2[1];
    float d = lmax - lmin + (float)1e-6;

    unsigned int lipk[4];   // 16 quantized L values packed 4x u8 per word
    #pragma unroll
    for (int it = 0; it < 4; it++) {
        unsigned int pk = 0;
        #pragma unroll
        for (int k = 0; k < 4; k++) {
            float l255 = (Lr[it * 4 + k] - lmin) / d * 255.0f;
            int li = (int)rintf(l255);
            li = min(max(li, 0), 255);
            pk |= (unsigned int)li << (8 * k);
            atomicAdd(&sh[li], 1);
        }
        lipk[it] = pk;
    }
    __syncthreads();
    int h = sh[t];
    // accumulate per-image histogram (device-scope atomic; 64 adds/bin)
    __hip_atomic_fetch_add(&hist_img[(n << 8) + t], h,
                           __ATOMIC_RELAXED, __HIP_MEMORY_SCOPE_AGENT);

    int cl = min(h, 32);   // limit = max(2*4096/256, 1) = 32
    int sum = cl;
    for (int off = 32; off; off >>= 1) sum += __shfl_down(sum, off, 64);
    if (ln == 0) wsum[wv] = sum;
    __syncthreads();
    int total = wsum[0] + wsum[1] + wsum[2] + wsum[3];
    int exc = TILE_AREA - total;
    sh[t] = 256 * cl + exc;                 // term*256, exact in int
    __syncthreads();
    for (int off = 1; off < 256; off <<= 1) {
        int v = sh[t];
        int add = (t >= off) ? sh[t - off] : 0;
        __syncthreads();
        sh[t] = v + add;
        __syncthreads();
    }
    ast_f(&lut_tile[b * 256 + t], rintf((float)sh[t] * (float)(255.0 / 1048576.0)));
    __threadfence();

    g.sync();

    // ------------- phase 3: eq LUT + bilinear CLAHE + recon -------------
    sh[t] = ald_i(&hist_img[(n << 8) + t]);
    __syncthreads();
    for (int off = 1; off < 256; off <<= 1) {
        int v = sh[t];
        int add = (t >= off) ? sh[t - off] : 0;
        __syncthreads();
        sh[t] = v + add;
        __syncthreads();
    }
    seq[t] = rintf((float)sh[t] * (float)(255.0 / (double)HW));

    const float* lt = lut_tile + n * 64 * 256;
    for (int j = t; j < 9 * 256; j += 256) {
        int q = j >> 8;
        int jy = q / 3, jx = q % 3;
        int gy = min(max(ty - 1 + jy, 0), 7);
        int gx = min(max(tx - 1 + jx, 0), 7);
        slut[j] = ald_f(&lt[(gy * 8 + gx) * 256 + (j & 255)]);
    }
    __syncthreads();

    float* o0 = out + (size_t)n * 3 * HW;
    float* o1 = out + (size_t)3 * NHW + (size_t)n * 3 * HW;

    #pragma unroll
    for (int it = 0; it < 4; it++) {
        int j = it * 1024 + t * 4;
        int r = j >> 6, c = j & 63;
        int y = ty * TILE + r;
        int xb = tx * TILE + c;
        int p = y * WW + xb;

        float cyf = fminf(fmaxf(((float)y + 0.5f) / 64.0f - 0.5f, 0.0f), 7.0f);
        int y0 = min((int)cyf, 6);
        float wy = cyf - (float)y0;
        int ly = y0 - ty + 1;

        float4 R0, G0, B0, R1, G1, B1;
        #pragma unroll
        for (int k = 0; k < 4; k++) {
            int li = (int)((lipk[it] >> (8 * k)) & 255u);
            float A  = Ar[it * 4 + k];
            float B2 = Brr[it * 4 + k];
            float l_eq = seq[li];

            int xc = xb + k;
            float cxf = fminf(fmaxf(((float)xc + 0.5f) / 64.0f - 0.5f, 0.0f), 7.0f);
            int x0 = min((int)cxf, 6);
            float wx = cxf - (float)x0;
            int lx = x0 - tx + 1;
            int base = ((ly * 3 + lx) << 8) + li;
            float v00 = slut[base];
            float v01 = slut[base + 256];
            float v10 = slut[base + 768];
            float v11 = slut[base + 1024];
            float top = v00 * (1.0f - wx) + v01 * wx;
            float bot = v10 * (1.0f - wx) + v11 * wx;
            float l_cl = top * (1.0f - wy) + bot * wy;

            float R, G, B;
            lab2rgb255_f(l_eq * (float)(100.0 / 255.0), A, B2, &R, &G, &B);
            ((float*)&R0)[k] = R; ((float*)&G0)[k] = G; ((float*)&B0)[k] = B;
            lab2rgb255_f(l_cl * (float)(100.0 / 255.0), A, B2, &R, &G, &B);
            ((float*)&R1)[k] = R; ((float*)&G1)[k] = G; ((float*)&B1)[k] = B;
        }
        *(float4*)(o0 + p)          = R0;
        *(float4*)(o0 + HW + p)     = G0;
        *(float4*)(o0 + 2 * HW + p) = B0;
        *(float4*)(o1 + p)          = R1;
        *(float4*)(o1 + HW + p)     = G1;
        *(float4*)(o1 + 2 * HW + p) = B1;
    }
}

// ================= verified 3-kernel fallback (round-0, 172 µs) =================

__global__ void k1_lab(const float* __restrict__ x, float* __restrict__ Lbuf,
                       float* __restrict__ out, float* __restrict__ tmn,
                       float* __restrict__ tmx) {
    int n = blockIdx.y, tile = blockIdx.x;
    int b = (n << 6) + tile;
    int ty = tile >> 3, tx = tile & 7;
    int t = threadIdx.x;
    const float* img = x + (size_t)n * 3 * HW;
    float* Lp = Lbuf + (size_t)n * HW;
    float* o0 = out + (size_t)n * 3 * HW;

    float mn = 1e30f, mx = -1e30f;
    #pragma unroll
    for (int it = 0; it < 4; it++) {
        int j = it * 1024 + t * 4;
        int r = j >> 6, c = j & 63;
        int p = (ty * TILE + r) * WW + tx * TILE + c;
        float4 r4 = *(const float4*)(img + p);
        float4 g4 = *(const float4*)(img + HW + p);
        float4 b4 = *(const float4*)(img + 2 * HW + p);
        float4 L4, A4, B4;
        #pragma unroll
        for (int k = 0; k < 4; k++) {
            float rr = ((const float*)&r4)[k];
            float gg = ((const float*)&g4)[k];
            float bb = ((const float*)&b4)[k];
            float rl = srgb2lin_p(rr), gl = srgb2lin_p(gg), bl = srgb2lin_p(bb);
            float X = ((float)0.4124564 * rl + (float)0.3575761 * gl + (float)0.1804375 * bl) / (float)0.95047;
            float Y = ((float)0.2126729 * rl + (float)0.7151522 * gl + (float)0.072175  * bl);
            float Z = ((float)0.0193339 * rl + (float)0.119192  * gl + (float)0.9503041 * bl) / (float)1.08883;
            float fx = fwd_p(X), fy = fwd_p(Y), fz = fwd_p(Z);
            float L = 116.0f * fy - 16.0f;
            ((float*)&L4)[k] = L;
            ((float*)&A4)[k] = 500.0f * (fx - fy);
            ((float*)&B4)[k] = 200.0f * (fy - fz);
            mn = fminf(mn, L);
            mx = fmaxf(mx, L);
        }
        *(float4*)(Lp + p)          = L4;
        *(float4*)(o0 + HW + p)     = A4;
        *(float4*)(o0 + 2 * HW + p) = B4;
    }
    for (int off = 32; off; off >>= 1) {
        mn = fminf(mn, __shfl_down(mn, off, 64));
        mx = fmaxf(mx, __shfl_down(mx, off, 64));
    }
    __shared__ float smn[4], smx[4];
    int wv = t >> 6, ln = t & 63;
    if (ln == 0) { smn[wv] = mn; smx[wv] = mx; }
    __syncthreads();
    if (t == 0) {
        tmn[b] = fminf(fminf(smn[0], smn[1]), fminf(smn[2], smn[3]));
        tmx[b] = fmaxf(fmaxf(smx[0], smx[1]), fmaxf(smx[2], smx[3]));
    }
}

__global__ void k2_quant(const float* __restrict__ Lbuf, const float* __restrict__ tmn,
                         const float* __restrict__ tmx, unsigned char* __restrict__ li_arr,
                         int* __restrict__ hist_tile, float* __restrict__ lut_tile) {
    int n = blockIdx.y, tile = blockIdx.x;
    int b = (n << 6) + tile;
    int ty = tile >> 3, tx = tile & 7;
    int t = threadIdx.x;

    __shared__ int sh[256];
    __shared__ float sred2[2];
    __shared__ int wsum[4];

    if (t < 64) {
        float v = tmn[(n << 6) + t];
        for (int off = 32; off; off >>= 1) v = fminf(v, __shfl_down(v, off, 64));
        if (t == 0) sred2[0] = v;
    } else if (t < 128) {
        float v = tmx[(n << 6) + (t - 64)];
        for (int off = 32; off; off >>= 1) v = fmaxf(v, __shfl_down(v, off, 64));
        if (t == 64) sred2[1] = v;
    }
    sh[t] = 0;
    __syncthreads();
    float lmin = sred2[0], lmax = sred2[1];
    float d = lmax - lmin + (float)1e-6;

    const float* Lp = Lbuf + (size_t)n * HW;
    unsigned char* lio = li_arr + (size_t)n * HW;
    #pragma unroll
    for (int it = 0; it < 4; it++) {
        int j = it * 1024 + t * 4;
        int r = j >> 6, c = j & 63;
        int p = (ty * TILE + r) * WW + tx * TILE + c;
        float4 L4 = *(const float4*)(Lp + p);
        uchar4 li4;
        #pragma unroll
        for (int k = 0; k < 4; k++) {
            float l255 = (((const float*)&L4)[k] - lmin) / d * 255.0f;
            int li = (int)rintf(l255);
            li = min(max(li, 0), 255);
            ((unsigned char*)&li4)[k] = (unsigned char)li;
            atomicAdd(&sh[li], 1);
        }
        *(uchar4*)(lio + p) = li4;
    }
    __syncthreads();
    int h = sh[t];
    hist_tile[b * 256 + t] = h;

    int cl = min(h, 32);
    int sum = cl;
    for (int off = 32; off; off >>= 1) sum += __shfl_down(sum, off, 64);
    int wv = t >> 6, ln = t & 63;
    if (ln == 0) wsum[wv] = sum;
    __syncthreads();
    int total = wsum[0] + wsum[1] + wsum[2] + wsum[3];
    int exc = TILE_AREA - total;
    sh[t] = 256 * cl + exc;
    __syncthreads();
    for (int off = 1; off < 256; off <<= 1) {
        int v = sh[t];
        int add = (t >= off) ? sh[t - off] : 0;
        __syncthreads();
        sh[t] = v + add;
        __syncthreads();
    }
    lut_tile[b * 256 + t] = rintf((float)sh[t] * (float)(255.0 / 1048576.0));
}

__global__ void k3_recon(const unsigned char* __restrict__ li_arr,
                         const int* __restrict__ hist_tile,
                         const float* __restrict__ lut_tile,
                         float* out) {
    int n = blockIdx.y, tile = blockIdx.x;
    int ty = tile >> 3, tx = tile & 7;
    int t = threadIdx.x;

    __shared__ int   sscan[256];
    __shared__ float seq[256];
    __shared__ float slut[9 * 256];

    const int* ht = hist_tile + n * 64 * 256;
    int h2 = 0;
    for (int tile2 = 0; tile2 < 64; tile2++) h2 += ht[tile2 * 256 + t];
    sscan[t] = h2;
    __syncthreads();
    for (int off = 1; off < 256; off <<= 1) {
        int v = sscan[t];
        int add = (t >= off) ? sscan[t - off] : 0;
        __syncthreads();
        sscan[t] = v + add;
        __syncthreads();
    }
    seq[t] = rintf((float)sscan[t] * (float)(255.0 / (double)HW));

    const float* lt = lut_tile + n * 64 * 256;
    for (int j = t; j < 9 * 256; j += 256) {
        int q = j >> 8;
        int jy = q / 3, jx = q % 3;
        int gy = min(max(ty - 1 + jy, 0), 7);
        int gx = min(max(tx - 1 + jx, 0), 7);
        slut[j] = lt[(gy * 8 + gx) * 256 + (j & 255)];
    }
    __syncthreads();

    const unsigned char* lip = li_arr + (size_t)n * HW;
    float* o0 = out + (size_t)n * 3 * HW;
    float* o1 = out + (size_t)3 * NHW + (size_t)n * 3 * HW;

    #pragma unroll
    for (int it = 0; it < 4; it++) {
        int j = it * 1024 + t * 4;
        int r = j >> 6, c = j & 63;
        int y = ty * TILE + r;
        int xb = tx * TILE + c;
        int p = y * WW + xb;

        uchar4 li4 = *(const uchar4*)(lip + p);
        float4 a4 = *(const float4*)(o0 + HW + p);
        float4 b4 = *(const float4*)(o0 + 2 * HW + p);

        float cyf = fminf(fmaxf(((float)y + 0.5f) / 64.0f - 0.5f, 0.0f), 7.0f);
        int y0 = min((int)cyf, 6);
        float wy = cyf - (float)y0;
        int ly = y0 - ty + 1;

        float4 R0, G0, B0, R1, G1, B1;
        #pragma unroll
        for (int k = 0; k < 4; k++) {
            int li = ((const unsigned char*)&li4)[k];
            float A  = ((const float*)&a4)[k];
            float B2 = ((const float*)&b4)[k];
            float l_eq = seq[li];

            int xc = xb + k;
            float cxf = fminf(fmaxf(((float)xc + 0.5f) / 64.0f - 0.5f, 0.0f), 7.0f);
            int x0 = min((int)cxf, 6);
            float wx = cxf - (float)x0;
            int lx = x0 - tx + 1;
            int base = ((ly * 3 + lx) << 8) + li;
            float v00 = slut[base];
            float v01 = slut[base + 256];
            float v10 = slut[base + 768];
            float v11 = slut[base + 1024];
            float top = v00 * (1.0f - wx) + v01 * wx;
            float bot = v10 * (1.0f - wx) + v11 * wx;
            float l_cl = top * (1.0f - wy) + bot * wy;

            float R, G, B;
            lab2rgb255_f(l_eq * (float)(100.0 / 255.0), A, B2, &R, &G, &B);
            ((float*)&R0)[k] = R; ((float*)&G0)[k] = G; ((float*)&B0)[k] = B;
            lab2rgb255_f(l_cl * (float)(100.0 / 255.0), A, B2, &R, &G, &B);
            ((float*)&R1)[k] = R; ((float*)&G1)[k] = G; ((float*)&B1)[k] = B;
        }
        *(float4*)(o0 + p)          = R0;
        *(float4*)(o0 + HW + p)     = G0;
        *(float4*)(o0 + 2 * HW + p) = B0;
        *(float4*)(o1 + p)          = R1;
        *(float4*)(o1 + HW + p)     = G1;
        *(float4*)(o1 + 2 * HW + p) = B1;
    }
}

extern "C" void kernel_launch(void* const* d_in, const int* in_sizes, int n_in,
                              void* d_out, int out_size, void* d_ws, size_t ws_size,
                              hipStream_t stream) {
    const float* x = (const float*)d_in[0];
    float* out = (float*)d_out;
    char* ws = (char*)d_ws;

    // layout identical to the verified round-0 kernel; fused path reuses
    // the hist_tile region (first 16 KiB) as hist_img and shares lut_tile.
    float* Lbuf = (float*)ws;                                            // 16.8 MiB
    size_t off = (size_t)NHW * 4;
    unsigned char* li = (unsigned char*)(ws + off); off += NHW;          // 4.2 MiB
    int* hist_tile = (int*)(ws + off);    off += (size_t)NIMG * 64 * 256 * 4;  // 1 MiB
    float* lut_tile = (float*)(ws + off); off += (size_t)NIMG * 64 * 256 * 4;  // 1 MiB
    float* tmn = (float*)(ws + off);      off += 1024 * 4;
    float* tmx = (float*)(ws + off);      off += 1024 * 4;
    int* hist_img = hist_tile;  // NIMG*256*4 = 16 KiB, within hist_tile region

    dim3 grid(64, NIMG), block(256);
    void* args[] = {(void*)&x, (void*)&out, (void*)&tmn, (void*)&tmx,
                    (void*)&hist_img, (void*)&lut_tile};
    hipError_t e = hipLaunchCooperativeKernel((const void*)k_fused, grid, block,
                                              args, 0, stream);
    if (e != hipSuccess) {
        // cooperative launch unavailable -> verified 3-kernel path
        k1_lab<<<grid, 256, 0, stream>>>(x, Lbuf, out, tmn, tmx);
        k2_quant<<<grid, 256, 0, stream>>>(Lbuf, tmn, tmx, li, hist_tile, lut_tile);
        k3_recon<<<grid, 256, 0, stream>>>(li, hist_tile, lut_tile, out);
    }
}

// Round 3
// 421.800 us; speedup vs baseline: 2.1604x; 2.1604x over previous
//
#include <hip/hip_runtime.h>

#define NIMG 16
#define HH 512
#define WW 512
#define HW (HH * WW)
#define NHW (NIMG * HW)
#define TILE 64
#define TILE_AREA (TILE * TILE)
#define NBLOCKS (64 * NIMG)

#define EPSV ((float)(216.0 / 24389.0))
#define KAPV ((float)(24389.0 / 27.0))

// ---------- fast transcendental helpers (unchanged, verified) ----------

__device__ __forceinline__ float pow24(float t) {
    float l   = __builtin_amdgcn_logf(t);
    float r   = __builtin_amdgcn_exp2f(l);
    float dl  = (t - r) * __builtin_amdgcn_rcpf(r) * 1.4426950408889634f;
    float ehi = 2.4f * l;
    float elo = __builtin_fmaf(2.4f, l, -ehi) + 2.4f * dl;
    float p   = __builtin_amdgcn_exp2f(ehi);
    return __builtin_fmaf(p * 0.6931471805599453f, elo, p);
}

__device__ __forceinline__ float cbrt_p(float v) {
    float l  = __builtin_amdgcn_logf(v);
    float t  = __builtin_amdgcn_exp2f(l * (1.0f / 3.0f));
    float t2 = t * t;
    float num = __builtin_fmaf(-t2, t, v);
    return __builtin_fmaf(num, __builtin_amdgcn_rcpf(3.0f * t2), t);
}

__device__ __forceinline__ float srgb2lin_p(float c) {
    float lin = c / 12.92f;
    float t   = (c + 0.055f) / 1.055f;
    return (c <= 0.04045f) ? lin : pow24(t);
}

__device__ __forceinline__ float fwd_p(float v) {
    return (v > EPSV) ? cbrt_p(v) : (KAPV * v + 16.0f) / 116.0f;
}

__device__ __forceinline__ float lin2srgb_f(float c) {
    c = fmaxf(c, 0.0f);
    float lo = c * 12.92f;
    float p  = __builtin_amdgcn_exp2f(__builtin_amdgcn_logf(c) * (float)(1.0 / 2.4));
    float hi = 1.055f * p - 0.055f;
    float r  = (c <= 0.0031308f) ? lo : hi;
    return fminf(fmaxf(r, 0.0f), 1.0f);
}

__device__ __forceinline__ float finv_f(float f) {
    float f3 = f * f * f;
    return (f3 > EPSV) ? f3 : (116.0f * f - 16.0f) * (float)(27.0 / 24389.0);
}

__device__ __forceinline__ void lab2rgb255_f(float L, float a, float b,
                                             float* R, float* G, float* B) {
    float fy = (L + 16.0f) * (float)(1.0 / 116.0);
    float fx = fy + a * (float)(1.0 / 500.0);
    float fz = fy - b * (float)(1.0 / 200.0);
    float X = finv_f(fx) * 0.95047f;
    float Y = finv_f(fy);
    float Z = finv_f(fz) * 1.08883f;
    *R = lin2srgb_f((float)3.2404542 * X + (float)-1.5371385 * Y + (float)-0.4985314 * Z) * 255.0f;
    *G = lin2srgb_f((float)-0.969266 * X + (float)1.8760108  * Y + (float)0.041556   * Z) * 255.0f;
    *B = lin2srgb_f((float)0.0556434 * X + (float)-0.2040259 * Y + (float)1.0572252  * Z) * 255.0f;
}

// ---- cross-block data movement: RELAXED agent-scope atomics (sc1 path).
// Round 2 proved this path coherent cross-XCD; relaxed drops the per-access
// acquire/release fences that aren't needed (ordering comes from the barrier).
__device__ __forceinline__ void rst_f(float* p, float v) {
    __hip_atomic_store(p, v, __ATOMIC_RELAXED, __HIP_MEMORY_SCOPE_AGENT);
}
__device__ __forceinline__ float rld_f(const float* p) {
    return __hip_atomic_load(p, __ATOMIC_RELAXED, __HIP_MEMORY_SCOPE_AGENT);
}
__device__ __forceinline__ int rld_i(const int* p) {
    return __hip_atomic_load(p, __ATOMIC_RELAXED, __HIP_MEMORY_SCOPE_AGENT);
}

// Hand-rolled grid barrier (replaces cg::grid.sync(), which cost ~390 µs each
// and forced a register spill across its ABI call).
// Sound because: __threadfence drains each wave's vmcnt (sc1 stores reach the
// coherent point on completion); arrival RMW is ACQ_REL agent; consumers read
// cross-block data with sc1 atomic loads (never from stale L1/L2).
__device__ __forceinline__ void grid_barrier(int* ctr) {
    __threadfence();
    __syncthreads();
    if (threadIdx.x == 0) {
        __hip_atomic_fetch_add(ctr, 1, __ATOMIC_ACQ_REL, __HIP_MEMORY_SCOPE_AGENT);
        while (__hip_atomic_load(ctr, __ATOMIC_ACQUIRE, __HIP_MEMORY_SCOPE_AGENT)
               < NBLOCKS) {
            __builtin_amdgcn_s_sleep(4);
        }
    }
    __syncthreads();
}

// K0: zero barrier counters + per-image histogram. Kernel-boundary coherence
// makes plain stores safe. Tiny (1 block).
__global__ void k0_init(int* __restrict__ hist_img, int* __restrict__ ctr) {
    int t = threadIdx.x;
    if (t < 2) ctr[t] = 0;
    for (int j = t; j < NIMG * 256; j += 256) hist_img[j] = 0;
}

// Fused kernel, NORMAL launch. Grid 64x16 = 1024 blocks; __launch_bounds__
// (256,4) -> exactly 4 blocks/CU x 256 CUs = whole grid co-resident, so the
// custom barrier cannot deadlock. LDS 11.8 KiB (4x = 47 KiB < 160).
__global__ __launch_bounds__(256, 4)
void k_fused(const float* __restrict__ x, float* __restrict__ out,
             float* __restrict__ tmn, float* __restrict__ tmx,
             int* __restrict__ hist_img, float* __restrict__ lut_tile,
             int* __restrict__ ctr) {
    const int n = blockIdx.y, tile = blockIdx.x;
    const int b = (n << 6) + tile;
    const int ty = tile >> 3, tx = tile & 7;
    const int t = threadIdx.x;

    __shared__ int   sh[256];
    __shared__ float smn[4], smx[4];
    __shared__ float sred2[2];
    __shared__ int   wsum[4];
    __shared__ float seq[256];
    __shared__ float slut[9 * 256];

    // persistent per-thread pixel data (16 px/thread, 48 VGPR)
    float Lr[16], Ar[16], Brr[16];

    const float* img = x + (size_t)n * 3 * HW;

    // ---------------- phase 1: RGB -> Lab, tile min/max ----------------
    float mn = 1e30f, mx = -1e30f;
    #pragma unroll
    for (int it = 0; it < 4; it++) {
        int j = it * 1024 + t * 4;
        int r = j >> 6, c = j & 63;
        int p = (ty * TILE + r) * WW + tx * TILE + c;
        float4 r4 = *(const float4*)(img + p);
        float4 g4 = *(const float4*)(img + HW + p);
        float4 b4 = *(const float4*)(img + 2 * HW + p);
        #pragma unroll
        for (int k = 0; k < 4; k++) {
            float rr = ((const float*)&r4)[k];
            float gg = ((const float*)&g4)[k];
            float bb = ((const float*)&b4)[k];
            float rl = srgb2lin_p(rr), gl = srgb2lin_p(gg), bl = srgb2lin_p(bb);
            float X = ((float)0.4124564 * rl + (float)0.3575761 * gl + (float)0.1804375 * bl) / (float)0.95047;
            float Y = ((float)0.2126729 * rl + (float)0.7151522 * gl + (float)0.072175  * bl);
            float Z = ((float)0.0193339 * rl + (float)0.119192  * gl + (float)0.9503041 * bl) / (float)1.08883;
            float fx = fwd_p(X), fy = fwd_p(Y), fz = fwd_p(Z);
            float L = 116.0f * fy - 16.0f;
            Lr[it * 4 + k]  = L;
            Ar[it * 4 + k]  = 500.0f * (fx - fy);
            Brr[it * 4 + k] = 200.0f * (fy - fz);
            mn = fminf(mn, L);
            mx = fmaxf(mx, L);
        }
    }
    for (int off = 32; off; off >>= 1) {
        mn = fminf(mn, __shfl_down(mn, off, 64));
        mx = fmaxf(mx, __shfl_down(mx, off, 64));
    }
    const int wv = t >> 6, ln = t & 63;
    if (ln == 0) { smn[wv] = mn; smx[wv] = mx; }
    __syncthreads();
    if (t == 0) {
        rst_f(&tmn[b], fminf(fminf(smn[0], smn[1]), fminf(smn[2], smn[3])));
        rst_f(&tmx[b], fmaxf(fmaxf(smx[0], smx[1]), fmaxf(smx[2], smx[3])));
    }

    grid_barrier(&ctr[0]);

    // -------- phase 2: image min/max, quantize, hist, CLAHE LUT --------
    if (t < 64) {
        float v = rld_f(&tmn[(n << 6) + t]);
        for (int off = 32; off; off >>= 1) v = fminf(v, __shfl_down(v, off, 64));
        if (t == 0) sred2[0] = v;
    } else if (t < 128) {
        float v = rld_f(&tmx[(n << 6) + (t - 64)]);
        for (int off = 32; off; off >>= 1) v = fmaxf(v, __shfl_down(v, off, 64));
        if (t == 64) sred2[1] = v;
    }
    sh[t] = 0;
    __syncthreads();
    float lmin = sred2[0], lmax = sred2[1];
    float d = lmax - lmin + (float)1e-6;

    unsigned int lipk[4];   // 16 quantized L values packed 4x u8 per word
    #pragma unroll
    for (int it = 0; it < 4; it++) {
        unsigned int pk = 0;
        #pragma unroll
        for (int k = 0; k < 4; k++) {
            float l255 = (Lr[it * 4 + k] - lmin) / d * 255.0f;
            int li = (int)rintf(l255);
            li = min(max(li, 0), 255);
            pk |= (unsigned int)li << (8 * k);
            atomicAdd(&sh[li], 1);
        }
        lipk[it] = pk;
    }
    __syncthreads();
    int h = sh[t];
    // accumulate per-image histogram (relaxed agent RMW; drained by barrier)
    __hip_atomic_fetch_add(&hist_img[(n << 8) + t], h,
                           __ATOMIC_RELAXED, __HIP_MEMORY_SCOPE_AGENT);

    int cl = min(h, 32);   // limit = max(2*4096/256, 1) = 32
    int sum = cl;
    for (int off = 32; off; off >>= 1) sum += __shfl_down(sum, off, 64);
    if (ln == 0) wsum[wv] = sum;
    __syncthreads();
    int total = wsum[0] + wsum[1] + wsum[2] + wsum[3];
    int exc = TILE_AREA - total;
    sh[t] = 256 * cl + exc;                 // term*256, exact in int
    __syncthreads();
    for (int off = 1; off < 256; off <<= 1) {
        int v = sh[t];
        int add = (t >= off) ? sh[t - off] : 0;
        __syncthreads();
        sh[t] = v + add;
        __syncthreads();
    }
    rst_f(&lut_tile[b * 256 + t], rintf((float)sh[t] * (float)(255.0 / 1048576.0)));

    grid_barrier(&ctr[1]);

    // ------------- phase 3: eq LUT + bilinear CLAHE + recon -------------
    sh[t] = rld_i(&hist_img[(n << 8) + t]);
    __syncthreads();
    for (int off = 1; off < 256; off <<= 1) {
        int v = sh[t];
        int add = (t >= off) ? sh[t - off] : 0;
        __syncthreads();
        sh[t] = v + add;
        __syncthreads();
    }
    seq[t] = rintf((float)sh[t] * (float)(255.0 / (double)HW));

    const float* lt = lut_tile + n * 64 * 256;
    for (int j = t; j < 9 * 256; j += 256) {
        int q = j >> 8;
        int jy = q / 3, jx = q % 3;
        int gy = min(max(ty - 1 + jy, 0), 7);
        int gx = min(max(tx - 1 + jx, 0), 7);
        slut[j] = rld_f(&lt[(gy * 8 + gx) * 256 + (j & 255)]);
    }
    __syncthreads();

    float* o0 = out + (size_t)n * 3 * HW;
    float* o1 = out + (size_t)3 * NHW + (size_t)n * 3 * HW;

    #pragma unroll
    for (int it = 0; it < 4; it++) {
        int j = it * 1024 + t * 4;
        int r = j >> 6, c = j & 63;
        int y = ty * TILE + r;
        int xb = tx * TILE + c;
        int p = y * WW + xb;

        float cyf = fminf(fmaxf(((float)y + 0.5f) / 64.0f - 0.5f, 0.0f), 7.0f);
        int y0 = min((int)cyf, 6);
        float wy = cyf - (float)y0;
        int ly = y0 - ty + 1;

        float4 R0, G0, B0, R1, G1, B1;
        #pragma unroll
        for (int k = 0; k < 4; k++) {
            int li = (int)((lipk[it] >> (8 * k)) & 255u);
            float A  = Ar[it * 4 + k];
            float B2 = Brr[it * 4 + k];
            float l_eq = seq[li];

            int xc = xb + k;
            float cxf = fminf(fmaxf(((float)xc + 0.5f) / 64.0f - 0.5f, 0.0f), 7.0f);
            int x0 = min((int)cxf, 6);
            float wx = cxf - (float)x0;
            int lx = x0 - tx + 1;
            int base = ((ly * 3 + lx) << 8) + li;
            float v00 = slut[base];
            float v01 = slut[base + 256];
            float v10 = slut[base + 768];
            float v11 = slut[base + 1024];
            float top = v00 * (1.0f - wx) + v01 * wx;
            float bot = v10 * (1.0f - wx) + v11 * wx;
            float l_cl = top * (1.0f - wy) + bot * wy;

            float R, G, B;
            lab2rgb255_f(l_eq * (float)(100.0 / 255.0), A, B2, &R, &G, &B);
            ((float*)&R0)[k] = R; ((float*)&G0)[k] = G; ((float*)&B0)[k] = B;
            lab2rgb255_f(l_cl * (float)(100.0 / 255.0), A, B2, &R, &G, &B);
            ((float*)&R1)[k] = R; ((float*)&G1)[k] = G; ((float*)&B1)[k] = B;
        }
        *(float4*)(o0 + p)          = R0;
        *(float4*)(o0 + HW + p)     = G0;
        *(float4*)(o0 + 2 * HW + p) = B0;
        *(float4*)(o1 + p)          = R1;
        *(float4*)(o1 + HW + p)     = G1;
        *(float4*)(o1 + 2 * HW + p) = B1;
    }
}

extern "C" void kernel_launch(void* const* d_in, const int* in_sizes, int n_in,
                              void* d_out, int out_size, void* d_ws, size_t ws_size,
                              hipStream_t stream) {
    const float* x = (const float*)d_in[0];
    float* out = (float*)d_out;
    char* ws = (char*)d_ws;

    int*   hist_img = (int*)ws;                                  // 16 KiB
    float* lut_tile = (float*)(ws + (size_t)64 * 1024);          // 1 MiB
    float* tmn = (float*)(ws + (size_t)64 * 1024 + (size_t)NIMG * 64 * 256 * 4);
    float* tmx = tmn + 1024;
    int*   ctr = (int*)(tmx + 1024);                             // 2 ints

    dim3 grid(64, NIMG), block(256);
    k0_init<<<1, 256, 0, stream>>>(hist_img, ctr);
    k_fused<<<grid, block, 0, stream>>>(x, out, tmn, tmx, hist_img, lut_tile, ctr);
}

// Round 4
// 361.800 us; speedup vs baseline: 2.5187x; 1.1658x over previous
//
#include <hip/hip_runtime.h>

#define NIMG 16
#define HH 512
#define WW 512
#define HW (HH * WW)
#define NHW (NIMG * HW)
#define TILE 64
#define TILE_AREA (TILE * TILE)

#define EPSV ((float)(216.0 / 24389.0))
#define KAPV ((float)(24389.0 / 27.0))

// ---------- fast transcendental helpers (unchanged, verified) ----------

__device__ __forceinline__ float pow24(float t) {
    float l   = __builtin_amdgcn_logf(t);
    float r   = __builtin_amdgcn_exp2f(l);
    float dl  = (t - r) * __builtin_amdgcn_rcpf(r) * 1.4426950408889634f;
    float ehi = 2.4f * l;
    float elo = __builtin_fmaf(2.4f, l, -ehi) + 2.4f * dl;
    float p   = __builtin_amdgcn_exp2f(ehi);
    return __builtin_fmaf(p * 0.6931471805599453f, elo, p);
}

__device__ __forceinline__ float cbrt_p(float v) {
    float l  = __builtin_amdgcn_logf(v);
    float t  = __builtin_amdgcn_exp2f(l * (1.0f / 3.0f));
    float t2 = t * t;
    float num = __builtin_fmaf(-t2, t, v);
    return __builtin_fmaf(num, __builtin_amdgcn_rcpf(3.0f * t2), t);
}

__device__ __forceinline__ float srgb2lin_p(float c) {
    float lin = c / 12.92f;
    float t   = (c + 0.055f) / 1.055f;
    return (c <= 0.04045f) ? lin : pow24(t);
}

__device__ __forceinline__ float fwd_p(float v) {
    return (v > EPSV) ? cbrt_p(v) : (KAPV * v + 16.0f) / 116.0f;
}

__device__ __forceinline__ float lin2srgb_f(float c) {
    c = fmaxf(c, 0.0f);
    float lo = c * 12.92f;
    float p  = __builtin_amdgcn_exp2f(__builtin_amdgcn_logf(c) * (float)(1.0 / 2.4));
    float hi = 1.055f * p - 0.055f;
    float r  = (c <= 0.0031308f) ? lo : hi;
    return fminf(fmaxf(r, 0.0f), 1.0f);
}

__device__ __forceinline__ float finv_f(float f) {
    float f3 = f * f * f;
    return (f3 > EPSV) ? f3 : (116.0f * f - 16.0f) * (float)(27.0 / 24389.0);
}

__device__ __forceinline__ void lab2rgb255_f(float L, float a, float b,
                                             float* R, float* G, float* B) {
    float fy = (L + 16.0f) * (float)(1.0 / 116.0);
    float fx = fy + a * (float)(1.0 / 500.0);
    float fz = fy - b * (float)(1.0 / 200.0);
    float X = finv_f(fx) * 0.95047f;
    float Y = finv_f(fy);
    float Z = finv_f(fz) * 1.08883f;
    *R = lin2srgb_f((float)3.2404542 * X + (float)-1.5371385 * Y + (float)-0.4985314 * Z) * 255.0f;
    *G = lin2srgb_f((float)-0.969266 * X + (float)1.8760108  * Y + (float)0.041556   * Z) * 255.0f;
    *B = lin2srgb_f((float)0.0556434 * X + (float)-0.2040259 * Y + (float)1.0572252  * Z) * 255.0f;
}

// ---- cross-block data: RELAXED agent-scope atomics (sc-coherent path;
// proven cross-XCD coherent in rounds 2-3). No per-access fences.
__device__ __forceinline__ void rst_f(float* p, float v) {
    __hip_atomic_store(p, v, __ATOMIC_RELAXED, __HIP_MEMORY_SCOPE_AGENT);
}
__device__ __forceinline__ float rld_f(const float* p) {
    return __hip_atomic_load(p, __ATOMIC_RELAXED, __HIP_MEMORY_SCOPE_AGENT);
}
__device__ __forceinline__ void rst_i(int* p, int v) {
    __hip_atomic_store(p, v, __ATOMIC_RELAXED, __HIP_MEMORY_SCOPE_AGENT);
}
__device__ __forceinline__ int rld_i(const int* p) {
    return __hip_atomic_load(p, __ATOMIC_RELAXED, __HIP_MEMORY_SCOPE_AGENT);
}

// Per-image barrier (64 blocks), monotone counter, two targets (64/128).
// KEY CHANGES vs round 3:
//  - spin with RELAXED loads: agent-ACQUIRE emits a cache-invalidate per
//    poll; ~1000 spinners polling every ~900cy invalidated every XCD's L2
//    every ~7cy continuously => the 240us stall. Relaxed polls read the
//    coherence point with NO invalidate. One ACQUIRE load after exit.
//  - per-image counters (padded 256B apart): blocks stall only on their
//    image's 64 peers; each CU hosts 4 different images' blocks, so other
//    images' compute hides the wait (cross-image pipelining).
// Soundness: producers end with __threadfence (vmcnt drain + L2 writeback)
// then RELEASE fetch_add; consumers observe count then read data with sc1
// relaxed loads straight from the coherence point.
__device__ __forceinline__ void image_barrier(int* ctr, int target) {
    __threadfence();
    __syncthreads();
    if (threadIdx.x == 0) {
        __hip_atomic_fetch_add(ctr, 1, __ATOMIC_RELEASE, __HIP_MEMORY_SCOPE_AGENT);
        while (__hip_atomic_load(ctr, __ATOMIC_RELAXED, __HIP_MEMORY_SCOPE_AGENT)
               < target) {
            __builtin_amdgcn_s_sleep(2);
        }
        (void)__hip_atomic_load(ctr, __ATOMIC_ACQUIRE, __HIP_MEMORY_SCOPE_AGENT);
    }
    __syncthreads();
}

// K0: zero the 16 per-image barrier counters (padded: one per 256B).
__global__ void k0_init(int* __restrict__ ctr) {
    int t = threadIdx.x;
    if (t < NIMG) ctr[t * 64] = 0;
}

// Fused kernel, normal launch. Grid 64x16 = 1024 blocks; launch_bounds
// (256,4) -> 4 blocks/CU x 256 CU = whole grid co-resident (LDS 11.8KiB*4
// = 47KiB < 160; VGPR<=128). Barriers are per-image only.
__global__ __launch_bounds__(256, 4)
void k_fused(const float* __restrict__ x, float* __restrict__ out,
             float* __restrict__ tmn, float* __restrict__ tmx,
             int* __restrict__ hist_img, float* __restrict__ lut_tile,
             int* __restrict__ ctr) {
    const int n = blockIdx.y, tile = blockIdx.x;
    const int b = (n << 6) + tile;
    const int ty = tile >> 3, tx = tile & 7;
    const int t = threadIdx.x;
    int* myctr = ctr + n * 64;   // 256B-padded per-image counter

    __shared__ int   sh[256];
    __shared__ float smn[4], smx[4];
    __shared__ float sred2[2];
    __shared__ int   wsum[4];
    __shared__ float seq[256];
    __shared__ float slut[9 * 256];

    // persistent per-thread pixel data (16 px/thread)
    float Lr[16], Ar[16], Brr[16];

    const float* img = x + (size_t)n * 3 * HW;

    // ---------------- phase 1: RGB -> Lab, tile min/max ----------------
    float mn = 1e30f, mx = -1e30f;
    #pragma unroll
    for (int it = 0; it < 4; it++) {
        int j = it * 1024 + t * 4;
        int r = j >> 6, c = j & 63;
        int p = (ty * TILE + r) * WW + tx * TILE + c;
        float4 r4 = *(const float4*)(img + p);
        float4 g4 = *(const float4*)(img + HW + p);
        float4 b4 = *(const float4*)(img + 2 * HW + p);
        #pragma unroll
        for (int k = 0; k < 4; k++) {
            float rr = ((const float*)&r4)[k];
            float gg = ((const float*)&g4)[k];
            float bb = ((const float*)&b4)[k];
            float rl = srgb2lin_p(rr), gl = srgb2lin_p(gg), bl = srgb2lin_p(bb);
            float X = ((float)0.4124564 * rl + (float)0.3575761 * gl + (float)0.1804375 * bl) / (float)0.95047;
            float Y = ((float)0.2126729 * rl + (float)0.7151522 * gl + (float)0.072175  * bl);
            float Z = ((float)0.0193339 * rl + (float)0.119192  * gl + (float)0.9503041 * bl) / (float)1.08883;
            float fx = fwd_p(X), fy = fwd_p(Y), fz = fwd_p(Z);
            float L = 116.0f * fy - 16.0f;
            Lr[it * 4 + k]  = L;
            Ar[it * 4 + k]  = 500.0f * (fx - fy);
            Brr[it * 4 + k] = 200.0f * (fy - fz);
            mn = fminf(mn, L);
            mx = fmaxf(mx, L);
        }
    }
    for (int off = 32; off; off >>= 1) {
        mn = fminf(mn, __shfl_down(mn, off, 64));
        mx = fmaxf(mx, __shfl_down(mx, off, 64));
    }
    const int wv = t >> 6, ln = t & 63;
    if (ln == 0) { smn[wv] = mn; smx[wv] = mx; }
    __syncthreads();
    if (t == 0) {
        rst_f(&tmn[b], fminf(fminf(smn[0], smn[1]), fminf(smn[2], smn[3])));
        rst_f(&tmx[b], fmaxf(fmaxf(smx[0], smx[1]), fmaxf(smx[2], smx[3])));
    }
    // tile-0 block zeroes this image's hist before arriving; RMWs happen
    // only after barrier 1 -> ordered.
    if (tile == 0) rst_i(&hist_img[(n << 8) + t], 0);

    image_barrier(myctr, 64);

    // -------- phase 2: image min/max, quantize, hist, CLAHE LUT --------
    if (t < 64) {
        float v = rld_f(&tmn[(n << 6) + t]);
        for (int off = 32; off; off >>= 1) v = fminf(v, __shfl_down(v, off, 64));
        if (t == 0) sred2[0] = v;
    } else if (t < 128) {
        float v = rld_f(&tmx[(n << 6) + (t - 64)]);
        for (int off = 32; off; off >>= 1) v = fmaxf(v, __shfl_down(v, off, 64));
        if (t == 64) sred2[1] = v;
    }
    sh[t] = 0;
    __syncthreads();
    float lmin = sred2[0], lmax = sred2[1];
    float d = lmax - lmin + (float)1e-6;

    unsigned int lipk[4];   // 16 quantized L values packed 4x u8 per word
    #pragma unroll
    for (int it = 0; it < 4; it++) {
        unsigned int pk = 0;
        #pragma unroll
        for (int k = 0; k < 4; k++) {
            float l255 = (Lr[it * 4 + k] - lmin) / d * 255.0f;
            int li = (int)rintf(l255);
            li = min(max(li, 0), 255);
            pk |= (unsigned int)li << (8 * k);
            atomicAdd(&sh[li], 1);
        }
        lipk[it] = pk;
    }
    __syncthreads();
    int h = sh[t];
    // accumulate per-image histogram (relaxed agent RMW; drained by barrier)
    __hip_atomic_fetch_add(&hist_img[(n << 8) + t], h,
                           __ATOMIC_RELAXED, __HIP_MEMORY_SCOPE_AGENT);

    int cl = min(h, 32);   // limit = max(2*4096/256, 1) = 32
    int sum = cl;
    for (int off = 32; off; off >>= 1) sum += __shfl_down(sum, off, 64);
    if (ln == 0) wsum[wv] = sum;
    __syncthreads();
    int total = wsum[0] + wsum[1] + wsum[2] + wsum[3];
    int exc = TILE_AREA - total;
    sh[t] = 256 * cl + exc;                 // term*256, exact in int
    __syncthreads();
    for (int off = 1; off < 256; off <<= 1) {
        int v = sh[t];
        int add = (t >= off) ? sh[t - off] : 0;
        __syncthreads();
        sh[t] = v + add;
        __syncthreads();
    }
    rst_f(&lut_tile[b * 256 + t], rintf((float)sh[t] * (float)(255.0 / 1048576.0)));

    image_barrier(myctr, 128);

    // ------------- phase 3: eq LUT + bilinear CLAHE + recon -------------
    sh[t] = rld_i(&hist_img[(n << 8) + t]);
    __syncthreads();
    for (int off = 1; off < 256; off <<= 1) {
        int v = sh[t];
        int add = (t >= off) ? sh[t - off] : 0;
        __syncthreads();
        sh[t] = v + add;
        __syncthreads();
    }
    seq[t] = rintf((float)sh[t] * (float)(255.0 / (double)HW));

    const float* lt = lut_tile + n * 64 * 256;
    for (int j = t; j < 9 * 256; j += 256) {
        int q = j >> 8;
        int jy = q / 3, jx = q % 3;
        int gy = min(max(ty - 1 + jy, 0), 7);
        int gx = min(max(tx - 1 + jx, 0), 7);
        slut[j] = rld_f(&lt[(gy * 8 + gx) * 256 + (j & 255)]);
    }
    __syncthreads();

    float* o0 = out + (size_t)n * 3 * HW;
    float* o1 = out + (size_t)3 * NHW + (size_t)n * 3 * HW;

    #pragma unroll
    for (int it = 0; it < 4; it++) {
        int j = it * 1024 + t * 4;
        int r = j >> 6, c = j & 63;
        int y = ty * TILE + r;
        int xb = tx * TILE + c;
        int p = y * WW + xb;

        float cyf = fminf(fmaxf(((float)y + 0.5f) / 64.0f - 0.5f, 0.0f), 7.0f);
        int y0 = min((int)cyf, 6);
        float wy = cyf - (float)y0;
        int ly = y0 - ty + 1;

        float4 R0, G0, B0, R1, G1, B1;
        #pragma unroll
        for (int k = 0; k < 4; k++) {
            int li = (int)((lipk[it] >> (8 * k)) & 255u);
            float A  = Ar[it * 4 + k];
            float B2 = Brr[it * 4 + k];
            float l_eq = seq[li];

            int xc = xb + k;
            float cxf = fminf(fmaxf(((float)xc + 0.5f) / 64.0f - 0.5f, 0.0f), 7.0f);
            int x0 = min((int)cxf, 6);
            float wx = cxf - (float)x0;
            int lx = x0 - tx + 1;
            int base = ((ly * 3 + lx) << 8) + li;
            float v00 = slut[base];
            float v01 = slut[base + 256];
            float v10 = slut[base + 768];
            float v11 = slut[base + 1024];
            float top = v00 * (1.0f - wx) + v01 * wx;
            float bot = v10 * (1.0f - wx) + v11 * wx;
            float l_cl = top * (1.0f - wy) + bot * wy;

            float R, G, B;
            lab2rgb255_f(l_eq * (float)(100.0 / 255.0), A, B2, &R, &G, &B);
            ((float*)&R0)[k] = R; ((float*)&G0)[k] = G; ((float*)&B0)[k] = B;
            lab2rgb255_f(l_cl * (float)(100.0 / 255.0), A, B2, &R, &G, &B);
            ((float*)&R1)[k] = R; ((float*)&G1)[k] = G; ((float*)&B1)[k] = B;
        }
        *(float4*)(o0 + p)          = R0;
        *(float4*)(o0 + HW + p)     = G0;
        *(float4*)(o0 + 2 * HW + p) = B0;
        *(float4*)(o1 + p)          = R1;
        *(float4*)(o1 + HW + p)     = G1;
        *(float4*)(o1 + 2 * HW + p) = B1;
    }
}

extern "C" void kernel_launch(void* const* d_in, const int* in_sizes, int n_in,
                              void* d_out, int out_size, void* d_ws, size_t ws_size,
                              hipStream_t stream) {
    const float* x = (const float*)d_in[0];
    float* out = (float*)d_out;
    char* ws = (char*)d_ws;

    int*   hist_img = (int*)ws;                                  // 16 KiB
    float* lut_tile = (float*)(ws + (size_t)64 * 1024);          // 1 MiB
    float* tmn = (float*)(ws + (size_t)64 * 1024 + (size_t)NIMG * 64 * 256 * 4);
    float* tmx = tmn + 1024;
    int*   ctr = (int*)(tmx + 1024);   // 16 counters, 256B apart (4 KiB)

    dim3 grid(64, NIMG), block(256);
    k0_init<<<1, 256, 0, stream>>>(ctr);
    k_fused<<<grid, block, 0, stream>>>(x, out, tmn, tmx, hist_img, lut_tile, ctr);
}

// Round 5
// 168.992 us; speedup vs baseline: 5.3924x; 2.1409x over previous
//
#include <hip/hip_runtime.h>

#define NIMG 16
#define HH 512
#define WW 512
#define HW (HH * WW)
#define NHW (NIMG * HW)
#define TILE 64
#define TILE_AREA (TILE * TILE)

#define EPSV ((float)(216.0 / 24389.0))
#define KAPV ((float)(24389.0 / 27.0))

// ---------- fast transcendental helpers (unchanged, verified) ----------

__device__ __forceinline__ float pow24(float t) {
    float l   = __builtin_amdgcn_logf(t);
    float r   = __builtin_amdgcn_exp2f(l);
    float dl  = (t - r) * __builtin_amdgcn_rcpf(r) * 1.4426950408889634f;
    float ehi = 2.4f * l;
    float elo = __builtin_fmaf(2.4f, l, -ehi) + 2.4f * dl;
    float p   = __builtin_amdgcn_exp2f(ehi);
    return __builtin_fmaf(p * 0.6931471805599453f, elo, p);
}

__device__ __forceinline__ float cbrt_p(float v) {
    float l  = __builtin_amdgcn_logf(v);
    float t  = __builtin_amdgcn_exp2f(l * (1.0f / 3.0f));
    float t2 = t * t;
    float num = __builtin_fmaf(-t2, t, v);
    return __builtin_fmaf(num, __builtin_amdgcn_rcpf(3.0f * t2), t);
}

__device__ __forceinline__ float srgb2lin_p(float c) {
    float lin = c / 12.92f;
    float t   = (c + 0.055f) / 1.055f;
    return (c <= 0.04045f) ? lin : pow24(t);
}

__device__ __forceinline__ float fwd_p(float v) {
    return (v > EPSV) ? cbrt_p(v) : (KAPV * v + 16.0f) / 116.0f;
}

__device__ __forceinline__ float lin2srgb_f(float c) {
    c = fmaxf(c, 0.0f);
    float lo = c * 12.92f;
    float p  = __builtin_amdgcn_exp2f(__builtin_amdgcn_logf(c) * (float)(1.0 / 2.4));
    float hi = 1.055f * p - 0.055f;
    float r  = (c <= 0.0031308f) ? lo : hi;
    return fminf(fmaxf(r, 0.0f), 1.0f);
}

__device__ __forceinline__ float finv_f(float f) {
    float f3 = f * f * f;
    return (f3 > EPSV) ? f3 : (116.0f * f - 16.0f) * (float)(27.0 / 24389.0);
}

__device__ __forceinline__ void lab2rgb255_f(float L, float a, float b,
                                             float* R, float* G, float* B) {
    float fy = (L + 16.0f) * (float)(1.0 / 116.0);
    float fx = fy + a * (float)(1.0 / 500.0);
    float fz = fy - b * (float)(1.0 / 200.0);
    float X = finv_f(fx) * 0.95047f;
    float Y = finv_f(fy);
    float Z = finv_f(fz) * 1.08883f;
    *R = lin2srgb_f((float)3.2404542 * X + (float)-1.5371385 * Y + (float)-0.4985314 * Z) * 255.0f;
    *G = lin2srgb_f((float)-0.969266 * X + (float)1.8760108  * Y + (float)0.041556   * Z) * 255.0f;
    *B = lin2srgb_f((float)0.0556434 * X + (float)-0.2040259 * Y + (float)1.0572252  * Z) * 255.0f;
}

// K1: one block per 64x64 tile. Lab once; L -> Lbuf; a,b -> out0 ch1/ch2
// (scratch; K3's same thread reads before overwriting). Tile min/max ->
// tmn/tmx[b]. Tile-0 blocks zero hist_img (K1->K2 boundary orders it).
// No __launch_bounds__: compiler needs VGPRs for pixel-chain ILP
// (round-4 lesson: a 60-VGPR schedule is latency-bound on the trans chains).
__global__ void k1_lab(const float* __restrict__ x, float* __restrict__ Lbuf,
                       float* __restrict__ out, float* __restrict__ tmn,
                       float* __restrict__ tmx, int* __restrict__ hist_img) {
    int n = blockIdx.y, tile = blockIdx.x;
    int b = (n << 6) + tile;
    int ty = tile >> 3, tx = tile & 7;
    int t = threadIdx.x;
    const float* img = x + (size_t)n * 3 * HW;
    float* Lp = Lbuf + (size_t)n * HW;
    float* o0 = out + (size_t)n * 3 * HW;

    if (tile == 0) hist_img[(n << 8) + t] = 0;

    float mn = 1e30f, mx = -1e30f;
    #pragma unroll
    for (int it = 0; it < 4; it++) {
        int j = it * 1024 + t * 4;
        int r = j >> 6, c = j & 63;
        int p = (ty * TILE + r) * WW + tx * TILE + c;
        float4 r4 = *(const float4*)(img + p);
        float4 g4 = *(const float4*)(img + HW + p);
        float4 b4 = *(const float4*)(img + 2 * HW + p);
        float4 L4, A4, B4;
        #pragma unroll
        for (int k = 0; k < 4; k++) {
            float rr = ((const float*)&r4)[k];
            float gg = ((const float*)&g4)[k];
            float bb = ((const float*)&b4)[k];
            float rl = srgb2lin_p(rr), gl = srgb2lin_p(gg), bl = srgb2lin_p(bb);
            float X = ((float)0.4124564 * rl + (float)0.3575761 * gl + (float)0.1804375 * bl) / (float)0.95047;
            float Y = ((float)0.2126729 * rl + (float)0.7151522 * gl + (float)0.072175  * bl);
            float Z = ((float)0.0193339 * rl + (float)0.119192  * gl + (float)0.9503041 * bl) / (float)1.08883;
            float fx = fwd_p(X), fy = fwd_p(Y), fz = fwd_p(Z);
            float L = 116.0f * fy - 16.0f;
            ((float*)&L4)[k] = L;
            ((float*)&A4)[k] = 500.0f * (fx - fy);
            ((float*)&B4)[k] = 200.0f * (fy - fz);
            mn = fminf(mn, L);
            mx = fmaxf(mx, L);
        }
        *(float4*)(Lp + p)          = L4;
        *(float4*)(o0 + HW + p)     = A4;
        *(float4*)(o0 + 2 * HW + p) = B4;
    }
    for (int off = 32; off; off >>= 1) {
        mn = fminf(mn, __shfl_down(mn, off, 64));
        mx = fmaxf(mx, __shfl_down(mx, off, 64));
    }
    __shared__ float smn[4], smx[4];
    int wv = t >> 6, ln = t & 63;
    if (ln == 0) { smn[wv] = mn; smx[wv] = mx; }
    __syncthreads();
    if (t == 0) {
        tmn[b] = fminf(fminf(smn[0], smn[1]), fminf(smn[2], smn[3]));
        tmx[b] = fmaxf(fmaxf(smx[0], smx[1]), fmaxf(smx[2], smx[3]));
    }
}

// K2: per tile: reduce image min/max from 64 tile entries, quantize L,
// store li (uchar4), LDS hist, accumulate per-image hist (global atomics;
// replaces K3's 64x256 re-read loop), CLAHE LUT (exact int scan).
__global__ void k2_quant(const float* __restrict__ Lbuf, const float* __restrict__ tmn,
                         const float* __restrict__ tmx, unsigned char* __restrict__ li_arr,
                         int* __restrict__ hist_img, float* __restrict__ lut_tile) {
    int n = blockIdx.y, tile = blockIdx.x;
    int b = (n << 6) + tile;
    int ty = tile >> 3, tx = tile & 7;
    int t = threadIdx.x;

    __shared__ int sh[256];
    __shared__ float sred2[2];
    __shared__ int wsum[4];

    if (t < 64) {
        float v = tmn[(n << 6) + t];
        for (int off = 32; off; off >>= 1) v = fminf(v, __shfl_down(v, off, 64));
        if (t == 0) sred2[0] = v;
    } else if (t < 128) {
        float v = tmx[(n << 6) + (t - 64)];
        for (int off = 32; off; off >>= 1) v = fmaxf(v, __shfl_down(v, off, 64));
        if (t == 64) sred2[1] = v;
    }
    sh[t] = 0;
    __syncthreads();
    float lmin = sred2[0], lmax = sred2[1];
    float d = lmax - lmin + (float)1e-6;

    const float* Lp = Lbuf + (size_t)n * HW;
    unsigned char* lio = li_arr + (size_t)n * HW;
    #pragma unroll
    for (int it = 0; it < 4; it++) {
        int j = it * 1024 + t * 4;
        int r = j >> 6, c = j & 63;
        int p = (ty * TILE + r) * WW + tx * TILE + c;
        float4 L4 = *(const float4*)(Lp + p);
        uchar4 li4;
        #pragma unroll
        for (int k = 0; k < 4; k++) {
            float l255 = (((const float*)&L4)[k] - lmin) / d * 255.0f;
            int li = (int)rintf(l255);
            li = min(max(li, 0), 255);
            ((unsigned char*)&li4)[k] = (unsigned char)li;
            atomicAdd(&sh[li], 1);
        }
        *(uchar4*)(lio + p) = li4;
    }
    __syncthreads();
    int h = sh[t];
    // per-image histogram: integer adds, order-free => bit-identical eq LUT
    atomicAdd(&hist_img[(n << 8) + t], h);

    int cl = min(h, 32);   // limit = max(2*4096/256, 1) = 32
    int sum = cl;
    for (int off = 32; off; off >>= 1) sum += __shfl_down(sum, off, 64);
    int wv = t >> 6, ln = t & 63;
    if (ln == 0) wsum[wv] = sum;
    __syncthreads();
    int total = wsum[0] + wsum[1] + wsum[2] + wsum[3];
    int exc = TILE_AREA - total;
    sh[t] = 256 * cl + exc;                 // term*256, exact in int
    __syncthreads();
    for (int off = 1; off < 256; off <<= 1) {
        int v = sh[t];
        int add = (t >= off) ? sh[t - off] : 0;
        __syncthreads();
        sh[t] = v + add;
        __syncthreads();
    }
    lut_tile[b * 256 + t] = rintf((float)sh[t] * (float)(255.0 / 1048576.0));
}

// K3: per tile: eq LUT from per-image hist (256 loads, was 64x256),
// 9 neighbor tile LUTs in LDS, read li + a,b, write both outputs.
__global__ void k3_recon(const unsigned char* __restrict__ li_arr,
                         const int* __restrict__ hist_img,
                         const float* __restrict__ lut_tile,
                         float* out) {
    int n = blockIdx.y, tile = blockIdx.x;
    int ty = tile >> 3, tx = tile & 7;
    int t = threadIdx.x;

    __shared__ int   sscan[256];
    __shared__ float seq[256];
    __shared__ float slut[9 * 256];

    sscan[t] = hist_img[(n << 8) + t];
    __syncthreads();
    for (int off = 1; off < 256; off <<= 1) {
        int v = sscan[t];
        int add = (t >= off) ? sscan[t - off] : 0;
        __syncthreads();
        sscan[t] = v + add;
        __syncthreads();
    }
    seq[t] = rintf((float)sscan[t] * (float)(255.0 / (double)HW));

    const float* lt = lut_tile + n * 64 * 256;
    for (int j = t; j < 9 * 256; j += 256) {
        int q = j >> 8;
        int jy = q / 3, jx = q % 3;
        int gy = min(max(ty - 1 + jy, 0), 7);
        int gx = min(max(tx - 1 + jx, 0), 7);
        slut[j] = lt[(gy * 8 + gx) * 256 + (j & 255)];
    }
    __syncthreads();

    const unsigned char* lip = li_arr + (size_t)n * HW;
    float* o0 = out + (size_t)n * 3 * HW;
    float* o1 = out + (size_t)3 * NHW + (size_t)n * 3 * HW;

    #pragma unroll
    for (int it = 0; it < 4; it++) {
        int j = it * 1024 + t * 4;
        int r = j >> 6, c = j & 63;
        int y = ty * TILE + r;
        int xb = tx * TILE + c;
        int p = y * WW + xb;

        uchar4 li4 = *(const uchar4*)(lip + p);
        float4 a4 = *(const float4*)(o0 + HW + p);       // a (from K1)
        float4 b4 = *(const float4*)(o0 + 2 * HW + p);   // b (from K1)

        float cyf = fminf(fmaxf(((float)y + 0.5f) / 64.0f - 0.5f, 0.0f), 7.0f);
        int y0 = min((int)cyf, 6);
        float wy = cyf - (float)y0;
        int ly = y0 - ty + 1;

        float4 R0, G0, B0, R1, G1, B1;
        #pragma unroll
        for (int k = 0; k < 4; k++) {
            int li = ((const unsigned char*)&li4)[k];
            float A  = ((const float*)&a4)[k];
            float B2 = ((const float*)&b4)[k];
            float l_eq = seq[li];

            int xc = xb + k;
            float cxf = fminf(fmaxf(((float)xc + 0.5f) / 64.0f - 0.5f, 0.0f), 7.0f);
            int x0 = min((int)cxf, 6);
            float wx = cxf - (float)x0;
            int lx = x0 - tx + 1;
            int base = ((ly * 3 + lx) << 8) + li;
            float v00 = slut[base];
            float v01 = slut[base + 256];
            float v10 = slut[base + 768];
            float v11 = slut[base + 1024];
            float top = v00 * (1.0f - wx) + v01 * wx;
            float bot = v10 * (1.0f - wx) + v11 * wx;
            float l_cl = top * (1.0f - wy) + bot * wy;

            float R, G, B;
            lab2rgb255_f(l_eq * (float)(100.0 / 255.0), A, B2, &R, &G, &B);
            ((float*)&R0)[k] = R; ((float*)&G0)[k] = G; ((float*)&B0)[k] = B;
            lab2rgb255_f(l_cl * (float)(100.0 / 255.0), A, B2, &R, &G, &B);
            ((float*)&R1)[k] = R; ((float*)&G1)[k] = G; ((float*)&B1)[k] = B;
        }
        *(float4*)(o0 + p)          = R0;
        *(float4*)(o0 + HW + p)     = G0;
        *(float4*)(o0 + 2 * HW + p) = B0;
        *(float4*)(o1 + p)          = R1;
        *(float4*)(o1 + HW + p)     = G1;
        *(float4*)(o1 + 2 * HW + p) = B1;
    }
}

extern "C" void kernel_launch(void* const* d_in, const int* in_sizes, int n_in,
                              void* d_out, int out_size, void* d_ws, size_t ws_size,
                              hipStream_t stream) {
    const float* x = (const float*)d_in[0];
    float* out = (float*)d_out;
    char* ws = (char*)d_ws;

    float* Lbuf = (float*)ws;                             // 16.8 MiB
    size_t off = (size_t)NHW * 4;
    unsigned char* li = (unsigned char*)(ws + off); off += NHW;          // 4.2 MiB
    int* hist_img = (int*)(ws + off);     off += (size_t)NIMG * 256 * 4; // 16 KiB
    float* lut_tile = (float*)(ws + off); off += (size_t)NIMG * 64 * 256 * 4;  // 1 MiB
    float* tmn = (float*)(ws + off);      off += 1024 * 4;
    float* tmx = (float*)(ws + off);      off += 1024 * 4;

    dim3 grid(64, NIMG);
    k1_lab<<<grid, 256, 0, stream>>>(x, Lbuf, out, tmn, tmx, hist_img);
    k2_quant<<<grid, 256, 0, stream>>>(Lbuf, tmn, tmx, li, hist_img, lut_tile);
    k3_recon<<<grid, 256, 0, stream>>>(li, hist_img, lut_tile, out);
}